// Round 1
// baseline (14647.621 us; speedup 1.0000x reference)
//
#include <hip/hip_runtime.h>

#define T_STEPS 4096
#define IDIM 2048
#define HDIM 2048
#define G4DIM 8192

typedef __attribute__((ext_vector_type(8))) short short8;
typedef __attribute__((ext_vector_type(4))) float f32x4;

__device__ __forceinline__ unsigned short f2bf(float f) {
  unsigned int u = __float_as_uint(f);
  u += 0x7fffu + ((u >> 16) & 1u);
  return (unsigned short)(u >> 16);
}
__device__ __forceinline__ float bf2f(unsigned short h) {
  return __uint_as_float(((unsigned int)h) << 16);
}

// C[M,N] = act( sum_k A[m,k]*B[n,k] + bias[n] )
// A: fp32 [M,K] row-major; B: fp32 [N,K] row-major (i.e. B^T form).
// Split-bf16: each fp32 -> hi+lo bf16; 3 MFMA passes (hi*hi + hi*lo + lo*hi)
// gives ~fp32-level accuracy at 1/3 of bf16 MFMA rate.
template <int ACT_SIGMOID, int OUT_BF16>
__global__ __launch_bounds__(256) void gemm_bt(
    const float* __restrict__ A, const float* __restrict__ B,
    const float* __restrict__ bias, void* __restrict__ Cout,
    int M, int N, int K)
{
  // 40 = 32 + 8 pad (16B) -> row stride 80 B = 20 banks: 2-way max (free)
  __shared__ short Ah[64][40];
  __shared__ short Al[64][40];
  __shared__ short Bh[64][40];
  __shared__ short Bl[64][40];
  const int tid  = threadIdx.x;
  const int wave = tid >> 6, lane = tid & 63;
  const int bn = blockIdx.x * 64, bm = blockIdx.y * 64;
  const int srow = tid >> 2, sc8 = (tid & 3) * 8;     // staging: 64 rows x 4 chunks of 8
  const int wm = (wave >> 1) * 32, wn = (wave & 1) * 32;
  const int lq = lane >> 4, lr = lane & 15;           // quad, index-in-tile
  f32x4 acc[2][2] = {};

  for (int k0 = 0; k0 < K; k0 += 32) {
    __syncthreads();
    {   // stage A tile (64x32 fp32 -> hi/lo bf16)
      const float* src = A + (size_t)(bm + srow) * K + k0 + sc8;
      float4 v0 = *(const float4*)(src);
      float4 v1 = *(const float4*)(src + 4);
      float vv[8] = {v0.x, v0.y, v0.z, v0.w, v1.x, v1.y, v1.z, v1.w};
      short8 vh, vl;
      #pragma unroll
      for (int i = 0; i < 8; ++i) {
        unsigned short hb = f2bf(vv[i]);
        vh[i] = (short)hb;
        vl[i] = (short)f2bf(vv[i] - bf2f(hb));
      }
      *(short8*)&Ah[srow][sc8] = vh;
      *(short8*)&Al[srow][sc8] = vl;
    }
    {   // stage B tile
      const float* src = B + (size_t)(bn + srow) * K + k0 + sc8;
      float4 v0 = *(const float4*)(src);
      float4 v1 = *(const float4*)(src + 4);
      float vv[8] = {v0.x, v0.y, v0.z, v0.w, v1.x, v1.y, v1.z, v1.w};
      short8 vh, vl;
      #pragma unroll
      for (int i = 0; i < 8; ++i) {
        unsigned short hb = f2bf(vv[i]);
        vh[i] = (short)hb;
        vl[i] = (short)f2bf(vv[i] - bf2f(hb));
      }
      *(short8*)&Bh[srow][sc8] = vh;
      *(short8*)&Bl[srow][sc8] = vl;
    }
    __syncthreads();

    // fragments: lane holds 8 contiguous K elems; row/col = lane&15, k = (lane>>4)*8
    short8 ah0 = *(const short8*)&Ah[wm +      lr][lq * 8];
    short8 al0 = *(const short8*)&Al[wm +      lr][lq * 8];
    short8 ah1 = *(const short8*)&Ah[wm + 16 + lr][lq * 8];
    short8 al1 = *(const short8*)&Al[wm + 16 + lr][lq * 8];
    short8 bh0 = *(const short8*)&Bh[wn +      lr][lq * 8];
    short8 bl0 = *(const short8*)&Bl[wn +      lr][lq * 8];
    short8 bh1 = *(const short8*)&Bh[wn + 16 + lr][lq * 8];
    short8 bl1 = *(const short8*)&Bl[wn + 16 + lr][lq * 8];

    acc[0][0] = __builtin_amdgcn_mfma_f32_16x16x32_bf16(ah0, bh0, acc[0][0], 0, 0, 0);
    acc[0][0] = __builtin_amdgcn_mfma_f32_16x16x32_bf16(ah0, bl0, acc[0][0], 0, 0, 0);
    acc[0][0] = __builtin_amdgcn_mfma_f32_16x16x32_bf16(al0, bh0, acc[0][0], 0, 0, 0);

    acc[0][1] = __builtin_amdgcn_mfma_f32_16x16x32_bf16(ah0, bh1, acc[0][1], 0, 0, 0);
    acc[0][1] = __builtin_amdgcn_mfma_f32_16x16x32_bf16(ah0, bl1, acc[0][1], 0, 0, 0);
    acc[0][1] = __builtin_amdgcn_mfma_f32_16x16x32_bf16(al0, bh1, acc[0][1], 0, 0, 0);

    acc[1][0] = __builtin_amdgcn_mfma_f32_16x16x32_bf16(ah1, bh0, acc[1][0], 0, 0, 0);
    acc[1][0] = __builtin_amdgcn_mfma_f32_16x16x32_bf16(ah1, bl0, acc[1][0], 0, 0, 0);
    acc[1][0] = __builtin_amdgcn_mfma_f32_16x16x32_bf16(al1, bh0, acc[1][0], 0, 0, 0);

    acc[1][1] = __builtin_amdgcn_mfma_f32_16x16x32_bf16(ah1, bh1, acc[1][1], 0, 0, 0);
    acc[1][1] = __builtin_amdgcn_mfma_f32_16x16x32_bf16(ah1, bl1, acc[1][1], 0, 0, 0);
    acc[1][1] = __builtin_amdgcn_mfma_f32_16x16x32_bf16(al1, bh1, acc[1][1], 0, 0, 0);
  }

  // epilogue: D row = (lane>>4)*4 + reg, col = lane&15  [m89/m91-verified]
  #pragma unroll
  for (int mi = 0; mi < 2; ++mi) {
    #pragma unroll
    for (int ni = 0; ni < 2; ++ni) {
      #pragma unroll
      for (int rr = 0; rr < 4; ++rr) {
        int row = bm + wm + mi * 16 + lq * 4 + rr;
        int col = bn + wn + ni * 16 + lr;
        float v = acc[mi][ni][rr];
        if (bias) v += bias[col];
        if (ACT_SIGMOID) v = 1.f / (1.f + __expf(-v));
        if (OUT_BF16)
          ((unsigned short*)Cout)[(size_t)row * N + col] = f2bf(v);
        else
          ((float*)Cout)[(size_t)row * N + col] = v;
      }
    }
  }
}

// Persistent-weight LSTM scan.
// 256 WGs x 512 threads; WG b owns hidden units [b*8, b*8+8) -> 32 gate rows.
// thread: kc = tid>>5 (K-chunk of 128), r = tid&31 (gate row). Weights: 128 fp32 VGPRs.
// Cross-WG sync: consumers spin on 0xAA poison in hs[t-1] (we memset it in-graph);
// per-step addresses are never reused -> no WAR hazards, no barrier, no deadlock.
__global__ __launch_bounds__(512, 2) void lstm_scan(
    const float* __restrict__ Whh,
    const float* __restrict__ b_ih, const float* __restrict__ b_hh,
    const unsigned short* __restrict__ gx,   // [T][8192] bf16
    float* __restrict__ hs)                  // [T][2048] fp32, pre-poisoned 0xAA
{
  const int b   = blockIdx.x;
  const int tid = threadIdx.x;
  const int kc  = tid >> 5;
  const int r   = tid & 31;
  const int gidx = r >> 3, ju = r & 7;
  const int grow = gidx * HDIM + b * 8 + ju;    // W_hh row (PyTorch gate order i,f,g,o)

  float w[128];
  {
    const float* wp = Whh + (size_t)grow * HDIM + kc * 128;
    #pragma unroll
    for (int i = 0; i < 32; ++i) {
      float4 v = *(const float4*)(wp + 4 * i);
      w[4*i] = v.x; w[4*i+1] = v.y; w[4*i+2] = v.z; w[4*i+3] = v.w;
    }
  }
  float bias_r = 0.f;
  if (tid < 32) {
    int br = (tid >> 3) * HDIM + b * 8 + (tid & 7);
    bias_r = b_ih[br] + b_hh[br];
  }
  float cval = 0.f;  // lanes tid<8 only
  __shared__ float h_lds[HDIM];
  __shared__ float partials[2][16][33];  // double-buffered; pad 33 -> conflict-free
  unsigned int* hs_u = (unsigned int*)hs;

  for (int t = 0; t < T_STEPS; ++t) {
    // gx for this step (independent of h -> issue before the poll)
    float gxv = 0.f;
    if (tid < 32)
      gxv = bf2f(gx[(size_t)t * G4DIM + (tid >> 3) * HDIM + b * 8 + (tid & 7)]);

    float4 h4;
    if (t > 0) {
      const unsigned int* p = hs_u + (size_t)(t - 1) * HDIM + kc * 128 + r * 4;
      unsigned int u0, u1, u2, u3;
      for (;;) {
        u0 = __hip_atomic_load(p + 0, __ATOMIC_RELAXED, __HIP_MEMORY_SCOPE_AGENT);
        u1 = __hip_atomic_load(p + 1, __ATOMIC_RELAXED, __HIP_MEMORY_SCOPE_AGENT);
        u2 = __hip_atomic_load(p + 2, __ATOMIC_RELAXED, __HIP_MEMORY_SCOPE_AGENT);
        u3 = __hip_atomic_load(p + 3, __ATOMIC_RELAXED, __HIP_MEMORY_SCOPE_AGENT);
        if (u0 != 0xAAAAAAAAu && u1 != 0xAAAAAAAAu &&
            u2 != 0xAAAAAAAAu && u3 != 0xAAAAAAAAu) break;
        __builtin_amdgcn_s_sleep(1);
      }
      h4.x = __uint_as_float(u0); h4.y = __uint_as_float(u1);
      h4.z = __uint_as_float(u2); h4.w = __uint_as_float(u3);
    } else {
      h4 = make_float4(0.f, 0.f, 0.f, 0.f);
    }

    // share chunk within the 32 same-kc lanes (same wave half) -> no barrier needed:
    // DS ops of one wave execute in order.
    *(float4*)&h_lds[kc * 128 + r * 4] = h4;

    float a0 = 0.f, a1 = 0.f, a2 = 0.f, a3 = 0.f;
    #pragma unroll
    for (int i = 0; i < 32; ++i) {
      float4 hv = *(const float4*)&h_lds[kc * 128 + i * 4];
      a0 += w[4*i]   * hv.x;
      a1 += w[4*i+1] * hv.y;
      a2 += w[4*i+2] * hv.z;
      a3 += w[4*i+3] * hv.w;
    }
    partials[t & 1][kc][r] = (a0 + a1) + (a2 + a3);
    __syncthreads();

    if (tid < 64) {  // wave 0 reduces + finalizes
      float gval = 0.f;
      if (tid < 32) {
        float s = gxv + bias_r;
        #pragma unroll
        for (int q = 0; q < 16; ++q) s += partials[t & 1][q][tid];
        gval = s;
      }
      float g_i = __shfl(gval, tid);
      float g_f = __shfl(gval, tid + 8);
      float g_g = __shfl(gval, tid + 16);
      float g_o = __shfl(gval, tid + 24);
      if (tid < 8) {
        float is = 1.f / (1.f + __expf(-g_i));
        float fs = 1.f / (1.f + __expf(-g_f));
        float os = 1.f / (1.f + __expf(-g_o));
        float e2 = __expf(-2.f * fabsf(g_g));
        float tg = (1.f - e2) / (1.f + e2);
        tg = (g_g < 0.f) ? -tg : tg;
        float cn = fs * cval + is * tg;
        cval = cn;
        float ec = __expf(-2.f * fabsf(cn));
        float tc = (1.f - ec) / (1.f + ec);
        tc = (cn < 0.f) ? -tc : tc;
        float hn = os * tc;
        __hip_atomic_store(hs_u + (size_t)t * HDIM + b * 8 + tid,
                           __float_as_uint(hn),
                           __ATOMIC_RELAXED, __HIP_MEMORY_SCOPE_AGENT);
      }
    }
    // no trailing barrier: partials double-buffered; t+2 reuse is gated by the
    // global dataflow (t+2 writes require h(t+1) which requires every WG's
    // wave-0 to have finished reading partials(t)).
  }
}

extern "C" void kernel_launch(void* const* d_in, const int* in_sizes, int n_in,
                              void* d_out, int out_size, void* d_ws, size_t ws_size,
                              hipStream_t stream) {
  (void)in_sizes; (void)n_in; (void)out_size; (void)ws_size;
  const float* x    = (const float*)d_in[0];   // [1,4096,2048]
  const float* W_ih = (const float*)d_in[1];   // [8192,2048]
  const float* W_hh = (const float*)d_in[2];   // [8192,2048]
  const float* b_ih = (const float*)d_in[3];   // [8192]
  const float* b_hh = (const float*)d_in[4];   // [8192]
  const float* Wo   = (const float*)d_in[5];   // [2048,2048]
  const float* bo   = (const float*)d_in[6];   // [2048]
  float* out = (float*)d_out;

  char* ws = (char*)d_ws;
  unsigned short* gx = (unsigned short*)ws;             // [4096][8192] bf16 = 64 MiB
  float* hs = (float*)(ws + (size_t)T_STEPS * G4DIM * 2); // [4096][2048] fp32 = 32 MiB

  // our own in-graph poison: the scan's dataflow sync depends on it
  hipMemsetAsync(hs, 0xAA, (size_t)T_STEPS * HDIM * sizeof(float), stream);

  // gx = x @ W_ih^T  (biases folded into the scan)
  gemm_bt<0, 1><<<dim3(G4DIM / 64, T_STEPS / 64), 256, 0, stream>>>(
      x, W_ih, nullptr, gx, T_STEPS, G4DIM, IDIM);

  lstm_scan<<<256, 512, 0, stream>>>(W_hh, b_ih, b_hh, gx, hs);

  // out = sigmoid(hs @ Wo^T + bo)
  gemm_bt<1, 0><<<dim3(IDIM / 64, T_STEPS / 64), 256, 0, stream>>>(
      hs, Wo, bo, out, T_STEPS, IDIM, HDIM);
}

// Round 2
// 12652.359 us; speedup vs baseline: 1.1577x; 1.1577x over previous
//
#include <hip/hip_runtime.h>

#define T_STEPS 4096
#define IDIM 2048
#define HDIM 2048
#define G4DIM 8192

typedef __attribute__((ext_vector_type(8))) short short8;
typedef __attribute__((ext_vector_type(4))) float f32x4;
typedef __attribute__((ext_vector_type(2))) float f32x2;

__device__ __forceinline__ unsigned short f2bf(float f) {
  unsigned int u = __float_as_uint(f);
  u += 0x7fffu + ((u >> 16) & 1u);
  return (unsigned short)(u >> 16);
}
__device__ __forceinline__ float bf2f(unsigned short h) {
  return __uint_as_float(((unsigned int)h) << 16);
}

// C[M,N] = act( sum_k A[m,k]*B[n,k] + bias[n] )
// A: fp32 [M,K] row-major; B: fp32 [N,K] row-major (i.e. B^T form).
// Split-bf16: each fp32 -> hi+lo bf16; 3 MFMA passes (hi*hi + hi*lo + lo*hi)
// gives ~fp32-level accuracy at 1/3 of bf16 MFMA rate.
template <int ACT_SIGMOID, int OUT_BF16>
__global__ __launch_bounds__(256) void gemm_bt(
    const float* __restrict__ A, const float* __restrict__ B,
    const float* __restrict__ bias, void* __restrict__ Cout,
    int M, int N, int K)
{
  // 40 = 32 + 8 pad (16B) -> row stride 80 B = 20 banks: 2-way max (free)
  __shared__ short Ah[64][40];
  __shared__ short Al[64][40];
  __shared__ short Bh[64][40];
  __shared__ short Bl[64][40];
  const int tid  = threadIdx.x;
  const int wave = tid >> 6, lane = tid & 63;
  const int bn = blockIdx.x * 64, bm = blockIdx.y * 64;
  const int srow = tid >> 2, sc8 = (tid & 3) * 8;     // staging: 64 rows x 4 chunks of 8
  const int wm = (wave >> 1) * 32, wn = (wave & 1) * 32;
  const int lq = lane >> 4, lr = lane & 15;           // quad, index-in-tile
  f32x4 acc[2][2] = {};

  for (int k0 = 0; k0 < K; k0 += 32) {
    __syncthreads();
    {   // stage A tile (64x32 fp32 -> hi/lo bf16)
      const float* src = A + (size_t)(bm + srow) * K + k0 + sc8;
      float4 v0 = *(const float4*)(src);
      float4 v1 = *(const float4*)(src + 4);
      float vv[8] = {v0.x, v0.y, v0.z, v0.w, v1.x, v1.y, v1.z, v1.w};
      short8 vh, vl;
      #pragma unroll
      for (int i = 0; i < 8; ++i) {
        unsigned short hb = f2bf(vv[i]);
        vh[i] = (short)hb;
        vl[i] = (short)f2bf(vv[i] - bf2f(hb));
      }
      *(short8*)&Ah[srow][sc8] = vh;
      *(short8*)&Al[srow][sc8] = vl;
    }
    {   // stage B tile
      const float* src = B + (size_t)(bn + srow) * K + k0 + sc8;
      float4 v0 = *(const float4*)(src);
      float4 v1 = *(const float4*)(src + 4);
      float vv[8] = {v0.x, v0.y, v0.z, v0.w, v1.x, v1.y, v1.z, v1.w};
      short8 vh, vl;
      #pragma unroll
      for (int i = 0; i < 8; ++i) {
        unsigned short hb = f2bf(vv[i]);
        vh[i] = (short)hb;
        vl[i] = (short)f2bf(vv[i] - bf2f(hb));
      }
      *(short8*)&Bh[srow][sc8] = vh;
      *(short8*)&Bl[srow][sc8] = vl;
    }
    __syncthreads();

    short8 ah0 = *(const short8*)&Ah[wm +      lr][lq * 8];
    short8 al0 = *(const short8*)&Al[wm +      lr][lq * 8];
    short8 ah1 = *(const short8*)&Ah[wm + 16 + lr][lq * 8];
    short8 al1 = *(const short8*)&Al[wm + 16 + lr][lq * 8];
    short8 bh0 = *(const short8*)&Bh[wn +      lr][lq * 8];
    short8 bl0 = *(const short8*)&Bl[wn +      lr][lq * 8];
    short8 bh1 = *(const short8*)&Bh[wn + 16 + lr][lq * 8];
    short8 bl1 = *(const short8*)&Bl[wn + 16 + lr][lq * 8];

    acc[0][0] = __builtin_amdgcn_mfma_f32_16x16x32_bf16(ah0, bh0, acc[0][0], 0, 0, 0);
    acc[0][0] = __builtin_amdgcn_mfma_f32_16x16x32_bf16(ah0, bl0, acc[0][0], 0, 0, 0);
    acc[0][0] = __builtin_amdgcn_mfma_f32_16x16x32_bf16(al0, bh0, acc[0][0], 0, 0, 0);

    acc[0][1] = __builtin_amdgcn_mfma_f32_16x16x32_bf16(ah0, bh1, acc[0][1], 0, 0, 0);
    acc[0][1] = __builtin_amdgcn_mfma_f32_16x16x32_bf16(ah0, bl1, acc[0][1], 0, 0, 0);
    acc[0][1] = __builtin_amdgcn_mfma_f32_16x16x32_bf16(al0, bh1, acc[0][1], 0, 0, 0);

    acc[1][0] = __builtin_amdgcn_mfma_f32_16x16x32_bf16(ah1, bh0, acc[1][0], 0, 0, 0);
    acc[1][0] = __builtin_amdgcn_mfma_f32_16x16x32_bf16(ah1, bl0, acc[1][0], 0, 0, 0);
    acc[1][0] = __builtin_amdgcn_mfma_f32_16x16x32_bf16(al1, bh0, acc[1][0], 0, 0, 0);

    acc[1][1] = __builtin_amdgcn_mfma_f32_16x16x32_bf16(ah1, bh1, acc[1][1], 0, 0, 0);
    acc[1][1] = __builtin_amdgcn_mfma_f32_16x16x32_bf16(ah1, bl1, acc[1][1], 0, 0, 0);
    acc[1][1] = __builtin_amdgcn_mfma_f32_16x16x32_bf16(al1, bh1, acc[1][1], 0, 0, 0);
  }

  // epilogue: D row = (lane>>4)*4 + reg, col = lane&15
  #pragma unroll
  for (int mi = 0; mi < 2; ++mi) {
    #pragma unroll
    for (int ni = 0; ni < 2; ++ni) {
      #pragma unroll
      for (int rr = 0; rr < 4; ++rr) {
        int row = bm + wm + mi * 16 + lq * 4 + rr;
        int col = bn + wn + ni * 16 + lr;
        float v = acc[mi][ni][rr];
        if (bias) v += bias[col];
        if (ACT_SIGMOID) v = 1.f / (1.f + __expf(-v));
        if (OUT_BF16)
          ((unsigned short*)Cout)[(size_t)row * N + col] = f2bf(v);
        else
          ((float*)Cout)[(size_t)row * N + col] = v;
      }
    }
  }
}

// Persistent-weight LSTM scan, v2.
// 256 WGs x 1024 threads; WG b owns hidden units [b*8, b*8+8) -> 32 gate rows.
// Thread (kc = tid>>3 in [0,128), u = tid&7): 4 gate-rows (gates 0..3 of unit u)
// over K-chunk [kc*16, kc*16+16). Weights: 64 fp32 VGPRs (under the 128-VGPR
// cap of __launch_bounds__(1024,4) -> no AGPR/scratch spill).
// h chunk: 16 floats, padded stride 20 dwords -> the 8 distinct broadcast
// addresses per ds_read_b128 tile all 32 banks conflict-free.
// Reduction: 3 __shfl_xor rounds (stride-8 lanes, same wave) fold 128 K-chunks
// -> 16 wave-partials; wave0 sums 16/row + finalizes.
// Cross-WG sync: consumers spin on 0xAA poison in hs[t-1] (we memset in-graph);
// per-step addresses never reused -> no WAR hazard, no barrier, no deadlock.
__global__ __launch_bounds__(1024, 4) void lstm_scan(
    const float* __restrict__ Whh,
    const float* __restrict__ b_ih, const float* __restrict__ b_hh,
    const unsigned short* __restrict__ gx,   // [T][8192] bf16
    float* __restrict__ hs)                  // [T][2048] fp32, poisoned 0xAA
{
  const int b   = blockIdx.x;
  const int tid = threadIdx.x;
  const int u   = tid & 7;       // unit within WG
  const int kc  = tid >> 3;      // K-chunk [0,128)
  const int wv  = tid >> 6;      // wave [0,16)

  // weights: gate g, k in [kc*16, kc*16+16)
  f32x2 w2[4][8];
  #pragma unroll
  for (int g = 0; g < 4; ++g) {
    const float* wp = Whh + (size_t)(g * HDIM + b * 8 + u) * HDIM + kc * 16;
    #pragma unroll
    for (int i = 0; i < 4; ++i) {
      float4 v = *(const float4*)(wp + 4 * i);
      w2[g][2 * i]     = f32x2{v.x, v.y};
      w2[g][2 * i + 1] = f32x2{v.z, v.w};
    }
  }
  float bias_r = 0.f;
  if (tid < 32) {
    int br = (tid >> 3) * HDIM + b * 8 + (tid & 7);
    bias_r = b_ih[br] + b_hh[br];
  }
  float cval = 0.f;  // lanes tid<8 only

  __shared__ float h_lds[128 * 20];        // padded chunks: stride 20 dwords
  __shared__ float partials[2][16][33];    // [buf][wave][row], pad 33
  unsigned int* hs_u = (unsigned int*)hs;

  for (int t = 0; t < T_STEPS; ++t) {
    // gx for this step (independent of h -> issue before the poll)
    float gxv = 0.f;
    if (tid < 32)
      gxv = bf2f(gx[(size_t)t * G4DIM + (tid >> 3) * HDIM + b * 8 + (tid & 7)]);

    // poll + load this thread's 2 h elements (global idx g0 = tid*2)
    f32x2 h2w;
    if (t > 0) {
      const unsigned int* p = hs_u + (size_t)(t - 1) * HDIM + tid * 2;
      unsigned int u0, u1;
      for (;;) {
        u0 = __hip_atomic_load(p + 0, __ATOMIC_RELAXED, __HIP_MEMORY_SCOPE_AGENT);
        u1 = __hip_atomic_load(p + 1, __ATOMIC_RELAXED, __HIP_MEMORY_SCOPE_AGENT);
        if (u0 != 0xAAAAAAAAu && u1 != 0xAAAAAAAAu) break;
        __builtin_amdgcn_s_sleep(1);
      }
      h2w = f32x2{__uint_as_float(u0), __uint_as_float(u1)};
    } else {
      h2w = f32x2{0.f, 0.f};
    }

    // stage into padded LDS; consumers of chunk kc are the 8 lanes that wrote
    // it (same wave) -> per-wave in-order DS pipe, no barrier needed.
    *(f32x2*)&h_lds[kc * 20 + u * 2] = h2w;

    f32x2 acc0{0.f, 0.f}, acc1{0.f, 0.f}, acc2{0.f, 0.f}, acc3{0.f, 0.f};
    #pragma unroll
    for (int i = 0; i < 4; ++i) {
      float4 hv = *(const float4*)&h_lds[kc * 20 + i * 4];
      f32x2 ha{hv.x, hv.y}, hb{hv.z, hv.w};
      acc0 += w2[0][2 * i] * ha;  acc0 += w2[0][2 * i + 1] * hb;
      acc1 += w2[1][2 * i] * ha;  acc1 += w2[1][2 * i + 1] * hb;
      acc2 += w2[2][2 * i] * ha;  acc2 += w2[2][2 * i + 1] * hb;
      acc3 += w2[3][2 * i] * ha;  acc3 += w2[3][2 * i + 1] * hb;
    }
    float s0 = acc0[0] + acc0[1];
    float s1 = acc1[0] + acc1[1];
    float s2 = acc2[0] + acc2[1];
    float s3 = acc3[0] + acc3[1];
    // fold the 8 K-chunks held by lanes {.., +8, .., +56} of this wave
    #pragma unroll
    for (int m = 8; m <= 32; m <<= 1) {
      s0 += __shfl_xor(s0, m, 64);
      s1 += __shfl_xor(s1, m, 64);
      s2 += __shfl_xor(s2, m, 64);
      s3 += __shfl_xor(s3, m, 64);
    }
    if ((tid & 56) == 0) {  // first 8 lanes of each wave
      partials[t & 1][wv][0 * 8 + u] = s0;
      partials[t & 1][wv][1 * 8 + u] = s1;
      partials[t & 1][wv][2 * 8 + u] = s2;
      partials[t & 1][wv][3 * 8 + u] = s3;
    }
    __syncthreads();

    if (tid < 64) {  // wave 0 reduces + finalizes
      float gval = 0.f;
      if (tid < 32) {
        float s = gxv + bias_r;
        #pragma unroll
        for (int q = 0; q < 16; ++q) s += partials[t & 1][q][tid];
        gval = s;
      }
      float g_i = __shfl(gval, tid);
      float g_f = __shfl(gval, tid + 8);
      float g_g = __shfl(gval, tid + 16);
      float g_o = __shfl(gval, tid + 24);
      if (tid < 8) {
        float is = 1.f / (1.f + __expf(-g_i));
        float fs = 1.f / (1.f + __expf(-g_f));
        float os = 1.f / (1.f + __expf(-g_o));
        float e2 = __expf(-2.f * fabsf(g_g));
        float tg = (1.f - e2) / (1.f + e2);
        tg = (g_g < 0.f) ? -tg : tg;
        float cn = fs * cval + is * tg;
        cval = cn;
        float ec = __expf(-2.f * fabsf(cn));
        float tc = (1.f - ec) / (1.f + ec);
        tc = (cn < 0.f) ? -tc : tc;
        float hn = os * tc;
        __hip_atomic_store(hs_u + (size_t)t * HDIM + b * 8 + tid,
                           __float_as_uint(hn),
                           __ATOMIC_RELAXED, __HIP_MEMORY_SCOPE_AGENT);
      }
    }
    // no trailing barrier: partials double-buffered; step t+2's writes are
    // gated by the global dataflow chain (our wave0's partials-read at t
    // happens-before its h(t) store -> producers' h(t+1) -> t+2 polls).
  }
}

extern "C" void kernel_launch(void* const* d_in, const int* in_sizes, int n_in,
                              void* d_out, int out_size, void* d_ws, size_t ws_size,
                              hipStream_t stream) {
  (void)in_sizes; (void)n_in; (void)out_size; (void)ws_size;
  const float* x    = (const float*)d_in[0];   // [1,4096,2048]
  const float* W_ih = (const float*)d_in[1];   // [8192,2048]
  const float* W_hh = (const float*)d_in[2];   // [8192,2048]
  const float* b_ih = (const float*)d_in[3];   // [8192]
  const float* b_hh = (const float*)d_in[4];   // [8192]
  const float* Wo   = (const float*)d_in[5];   // [2048,2048]
  const float* bo   = (const float*)d_in[6];   // [2048]
  float* out = (float*)d_out;

  char* ws = (char*)d_ws;
  unsigned short* gx = (unsigned short*)ws;               // 64 MiB bf16
  float* hs = (float*)(ws + (size_t)T_STEPS * G4DIM * 2); // 32 MiB fp32

  // our own in-graph poison: the scan's dataflow sync depends on it
  hipMemsetAsync(hs, 0xAA, (size_t)T_STEPS * HDIM * sizeof(float), stream);

  // gx = x @ W_ih^T  (biases folded into the scan)
  gemm_bt<0, 1><<<dim3(G4DIM / 64, T_STEPS / 64), 256, 0, stream>>>(
      x, W_ih, nullptr, gx, T_STEPS, G4DIM, IDIM);

  lstm_scan<<<256, 1024, 0, stream>>>(W_hh, b_ih, b_hh, gx, hs);

  // out = sigmoid(hs @ Wo^T + bo)
  gemm_bt<1, 0><<<dim3(IDIM / 64, T_STEPS / 64), 256, 0, stream>>>(
      hs, Wo, bo, out, T_STEPS, IDIM, HDIM);
}